// Round 2
// baseline (736.827 us; speedup 1.0000x reference)
//
#include <hip/hip_runtime.h>

// CRF NLL: B=256 batches, S=2048 steps, T=64 tags.
// Denominator (log-partition) = 256 independent sequential chains; run in exp
// space with per-step renormalization, f16-packed readlane broadcast + v_dot2.
#define BB 256
#define SS 2048
#define TT 64

typedef __fp16 half2v __attribute__((ext_vector_type(2)));

__device__ __forceinline__ float rfl_f(float x) {
  return __builtin_bit_cast(float, __builtin_amdgcn_readfirstlane(__builtin_bit_cast(int, x)));
}

// neighbor swap within lane pairs (quad_perm [1,0,3,2] = 0xB1)
__device__ __forceinline__ float dpp_swap1(float x) {
  int r = __builtin_amdgcn_update_dpp(0, __builtin_bit_cast(int, x), 0xB1, 0xF, 0xF, true);
  return __builtin_bit_cast(float, r);
}

__device__ __forceinline__ half2v i2h2(int x) { return __builtin_bit_cast(half2v, x); }

__device__ __forceinline__ float dot2acc(half2v a, half2v b, float c) {
#if __has_builtin(__builtin_amdgcn_fdot2)
  return __builtin_amdgcn_fdot2(a, b, c, false);
#else
  return c + (float)a[0] * (float)b[0] + (float)a[1] * (float)b[1];
#endif
}

// One forward-recurrence step.
// Invariant: alpha_j = (log2(q_j) + off2) * ln2, with q_0 == 1 after each step.
// E2[m] holds (exp(trans[2m][j]), exp(trans[2m+1][j])) * 2^-5 for this lane j.
// q broadcast copy is scaled by 2^-5; the combined 2^-10 is repaid via +10 in off2.
__device__ __forceinline__ void crf_step(float& q, float& off2, float emv,
                                         const half2v (&E2)[32]) {
  float x = __expf(emv);               // off the critical chain (dep: em only)
  float qs = q * 0.03125f;             // 2^-5
  float qn = dpp_swap1(qs);            // neighbor's scaled q
  int qpi = __builtin_bit_cast(int, __builtin_amdgcn_cvt_pkrtz(qs, qn));  // valid on even lanes
  float a0 = 0.f, a1 = 0.f, a2 = 0.f, a3 = 0.f;
#pragma unroll
  for (int m = 0; m < 8; ++m) {
    a0 = dot2acc(i2h2(__builtin_amdgcn_readlane(qpi, 8 * m + 0)), E2[4 * m + 0], a0);
    a1 = dot2acc(i2h2(__builtin_amdgcn_readlane(qpi, 8 * m + 2)), E2[4 * m + 1], a1);
    a2 = dot2acc(i2h2(__builtin_amdgcn_readlane(qpi, 8 * m + 4)), E2[4 * m + 2], a2);
    a3 = dot2acc(i2h2(__builtin_amdgcn_readlane(qpi, 8 * m + 6)), E2[4 * m + 3], a3);
  }
  float s = (a0 + a1) + (a2 + a3);
  float t = s * x;
  float v = rfl_f(t);                            // t at lane 0, > 0 always
  float r = __builtin_amdgcn_rcpf(v);
  q = t * r;                                     // renormalized: q_0 = 1
  off2 += __log2f(v) + 10.0f;                    // +10 repays the 2^-10 scaling
}

__device__ __forceinline__ void prefetch8(float (&buf)[8], int& mreg, int i0,
                                          const float* __restrict__ ep,
                                          const int* __restrict__ mp, int j) {
#pragma unroll
  for (int t = 0; t < 8; ++t) {
    int ii = i0 + t;
    ii = ii > SS - 1 ? SS - 1 : ii;             // clamp: harmless dup load
    buf[t] = ep[ii * TT];
  }
  int mi = i0 + (j & 7);
  int mc = mi > SS - 1 ? SS - 1 : mi;
  int ml = mp[mc];
  mreg = (mi > SS - 1) ? 0 : ml;                // OOB steps are masked off
}

__device__ __forceinline__ void process8(float& q, float& off2, const float (&buf)[8],
                                         int mreg, const half2v (&E2)[32]) {
  unsigned long long bal = __ballot(mreg != 0);
  if (bal == ~0ull) {                            // fast path: all 8 steps active
#pragma unroll
    for (int t = 0; t < 8; ++t) crf_step(q, off2, buf[t], E2);
  } else {                                       // rare: per-step uniform branch
#pragma unroll
    for (int t = 0; t < 8; ++t) {
      int mv = __builtin_amdgcn_readlane(mreg, t);
      if (mv) crf_step(q, off2, buf[t], E2);
    }
  }
}

__global__ __launch_bounds__(64) void crf_den_kernel(
    const float* __restrict__ em, const float* __restrict__ startT,
    const float* __restrict__ endT, const float* __restrict__ trans,
    const int* __restrict__ mask, const float* __restrict__ numer,
    float* __restrict__ out) {
  const int b = blockIdx.x;
  const int j = threadIdx.x;  // tag index, one wave per batch

  // E columns in registers: E2[m] = (e^{trans[2m][j]}, e^{trans[2m+1][j]}) * 2^-5
  half2v E2[32];
#pragma unroll
  for (int m = 0; m < 32; ++m) {
    float e0 = __expf(trans[(2 * m) * TT + j]) * 0.03125f;
    float e1 = __expf(trans[(2 * m + 1) * TT + j]) * 0.03125f;
    E2[m] = __builtin_amdgcn_cvt_pkrtz(e0, e1);
  }

  const float* ep = em + (size_t)b * SS * TT + j;
  const int* mp = mask + b * SS;

  // init: alpha0 = start + em[0]; normalize so q_0 = 1
  float a0v = startT[j] + ep[0];
  float a00 = rfl_f(a0v);
  float q = __expf(a0v - a00);
  float off2 = a00 * 1.4426950408889634f;  // log2-space offset

  // steps i = 1..2047 as 256 chunks of 8 (chunk 255 pads step 2048, masked off)
  float bufA[8], bufB[8];
  int mA, mB;
  prefetch8(bufA, mA, 1, ep, mp, j);
  for (int c = 0; c < 256; c += 2) {
    prefetch8(bufB, mB, 1 + 8 * (c + 1), ep, mp, j);
    process8(q, off2, bufA, mA, E2);
    prefetch8(bufA, mA, 1 + 8 * (c + 2), ep, mp, j);  // c+2==256: fully masked
    process8(q, off2, bufB, mB, E2);
  }

  // denominator = logsumexp_j(alpha_j + end_j)
  float alpha = (__log2f(q) + off2) * 0.69314718055994531f;
  float tj = alpha + endT[j];
  float mx = tj;
#pragma unroll
  for (int o = 32; o > 0; o >>= 1) mx = fmaxf(mx, __shfl_xor(mx, o, 64));
  float ex = __expf(tj - mx);
#pragma unroll
  for (int o = 32; o > 0; o >>= 1) ex += __shfl_xor(ex, o, 64);
  float den = mx + __logf(ex);

  if (j == 0) {
    float nm = numer[b];
    atomicAdd(out, (den - nm) * (1.0f / BB));
  }
}

__global__ __launch_bounds__(256) void crf_num_kernel(
    const float* __restrict__ em, const float* __restrict__ startT,
    const float* __restrict__ endT, const float* __restrict__ trans,
    const int* __restrict__ tags, const int* __restrict__ mask,
    float* __restrict__ numer) {
  const int b = blockIdx.x;
  const int t = threadIdx.x;
  const int* tg = tags + b * SS;
  const int* mk = mask + b * SS;
  const float* e = em + (size_t)b * SS * TT;
  float part = 0.f;
  int cnt = 0;
  for (int i = t; i < SS; i += 256) {
    int m = mk[i];
    cnt += m;
    if (i == 0) {
      part += startT[tg[0]] + e[tg[0]];
    } else if (m) {
      part += trans[tg[i - 1] * TT + tg[i]] + e[(size_t)i * TT + tg[i]];
    }
  }
  __shared__ float sp[4];
  __shared__ int sc[4];
#pragma unroll
  for (int o = 32; o > 0; o >>= 1) {
    part += __shfl_down(part, o, 64);
    cnt += __shfl_down(cnt, o, 64);
  }
  int wid = t >> 6;
  if ((t & 63) == 0) { sp[wid] = part; sc[wid] = cnt; }
  __syncthreads();
  if (t == 0) {
    float tot = sp[0] + sp[1] + sp[2] + sp[3];
    int ctot = sc[0] + sc[1] + sc[2] + sc[3];
    int last = tg[ctot - 1];
    numer[b] = tot + endT[last];
  }
}

extern "C" void kernel_launch(void* const* d_in, const int* in_sizes, int n_in,
                              void* d_out, int out_size, void* d_ws, size_t ws_size,
                              hipStream_t stream) {
  const float* em = (const float*)d_in[0];
  const float* startT = (const float*)d_in[1];
  const float* endT = (const float*)d_in[2];
  const float* trans = (const float*)d_in[3];
  const int* tags = (const int*)d_in[4];
  const int* mask = (const int*)d_in[5];
  float* out = (float*)d_out;
  float* numer = (float*)d_ws;  // 256 floats

  (void)hipMemsetAsync(out, 0, sizeof(float), stream);
  crf_num_kernel<<<BB, 256, 0, stream>>>(em, startT, endT, trans, tags, mask, numer);
  crf_den_kernel<<<BB, 64, 0, stream>>>(em, startT, endT, trans, mask, numer, out);
}

// Round 3
// 546.399 us; speedup vs baseline: 1.3485x; 1.3485x over previous
//
#include <hip/hip_runtime.h>

// CRF NLL: B=256 batches, S=2048 steps, T=64 tags.
// Denominator = 256 independent sequential chains, one wave each (lane = tag).
// Exp-space recurrence with exact power-of-2 renorm (no rcp/log2 per step),
// f16-packed broadcast via batched readlane (hazard-amortized) + v_dot2_f32_f16.
#define BB 256
#define SS 2048
#define TT 64

typedef __fp16 half2v __attribute__((ext_vector_type(2)));

__device__ __forceinline__ float rfl_f(float x) {
  return __builtin_bit_cast(float, __builtin_amdgcn_readfirstlane(__builtin_bit_cast(int, x)));
}

// neighbor swap within lane pairs (quad_perm [1,0,3,2] = 0xB1)
__device__ __forceinline__ float dpp_swap1(float x) {
  int r = __builtin_amdgcn_update_dpp(0, __builtin_bit_cast(int, x), 0xB1, 0xF, 0xF, true);
  return __builtin_bit_cast(float, r);
}

__device__ __forceinline__ half2v i2h2(int x) { return __builtin_bit_cast(half2v, x); }

__device__ __forceinline__ float dot2acc(half2v a, half2v b, float c) {
  return __builtin_amdgcn_fdot2(a, b, c, false);
}

__device__ __forceinline__ void sfence() {
#if __has_builtin(__builtin_amdgcn_sched_barrier)
  __builtin_amdgcn_sched_barrier(0);
#endif
}

// Invariant: alpha_j = ln2 * (log2(q_j) + gamma), q_0 in [2^-6, 2^-5).
// E2[m] = (exp(trans[2m][j]), exp(trans[2m+1][j])) * 2^-5 (f16 pair, this lane's j).
// gamma tracked as: gamma_init + esum - 116*nsteps  (esum/nsteps exact ints).
__device__ __forceinline__ void crf_step(float& q, int& esum, float x,
                                         const half2v (&E2)[32]) {
  float qn = dpp_swap1(q);
  int qpi = __builtin_bit_cast(int, __builtin_amdgcn_cvt_pkrtz(q, qn));  // even lanes valid
  int sg[32];
#pragma unroll
  for (int m = 0; m < 32; ++m) sg[m] = __builtin_amdgcn_readlane(qpi, 2 * m);
  sfence();  // keep all readlanes before all dots: amortize SGPR-write hazards
  float a0 = 0.f, a1 = 0.f, a2 = 0.f, a3 = 0.f;
#pragma unroll
  for (int m = 0; m < 8; ++m) {
    a0 = dot2acc(i2h2(sg[4 * m + 0]), E2[4 * m + 0], a0);
    a1 = dot2acc(i2h2(sg[4 * m + 1]), E2[4 * m + 1], a1);
    a2 = dot2acc(i2h2(sg[4 * m + 2]), E2[4 * m + 2], a2);
    a3 = dot2acc(i2h2(sg[4 * m + 3]), E2[4 * m + 3], a3);
  }
  float s = (a0 + a1) + (a2 + a3);
  float t = s * x;                       // t = Q' * 2^-(gamma+5), > 0
  float v = rfl_f(t);                    // lane-0 value, uniform
  int eb = __builtin_bit_cast(int, v) & 0x7f800000;
  float scale = __builtin_bit_cast(float, 0x7C000000 - eb);  // 2^(121-e), exact
  q = t * scale;                         // q_0 back in [2^-6, 2^-5)
  esum += (eb >> 23);                    // exact integer exponent bookkeeping
}

__device__ __forceinline__ void prefetch8(float (&buf)[8], int& mreg, int i0,
                                          const float* __restrict__ ep,
                                          const int* __restrict__ mp, int j) {
#pragma unroll
  for (int t = 0; t < 8; ++t) {
    int ii = i0 + t;
    ii = ii > SS - 1 ? SS - 1 : ii;      // clamp: harmless dup load
    buf[t] = ep[ii * TT];
  }
  int mi = i0 + (j & 7);
  int mc = mi > SS - 1 ? SS - 1 : mi;
  int ml = mp[mc];
  mreg = (mi > SS - 1) ? 0 : ml;         // OOB steps masked off
}

__device__ __forceinline__ void process8(float& q, int& esum, int& nsteps,
                                         const float (&buf)[8], int mreg,
                                         const half2v (&E2)[32]) {
  unsigned long long bal = __ballot(mreg != 0);
  if (bal == ~0ull) {                    // fast path: all 8 steps active
    float xs[8];
#pragma unroll
    for (int t = 0; t < 8; ++t) xs[t] = __expf(buf[t]);
#pragma unroll
    for (int t = 0; t < 8; ++t) crf_step(q, esum, xs[t], E2);
    nsteps += 8;
  } else {                               // rare: per-step uniform branch
#pragma unroll
    for (int t = 0; t < 8; ++t) {
      int mv = __builtin_amdgcn_readlane(mreg, t);
      if (mv) {
        crf_step(q, esum, __expf(buf[t]), E2);
        nsteps += 1;
      }
    }
  }
}

__global__ __launch_bounds__(64, 1) void crf_den_kernel(
    const float* __restrict__ em, const float* __restrict__ startT,
    const float* __restrict__ endT, const float* __restrict__ trans,
    const int* __restrict__ mask, const int* __restrict__ tags,
    const float* __restrict__ numerArr, const int* __restrict__ cntArr,
    float* __restrict__ out) {
  const int b = blockIdx.x;
  const int j = threadIdx.x;  // tag index, one wave per batch

  half2v E2[32];
#pragma unroll
  for (int m = 0; m < 32; ++m) {
    float e0 = __expf(trans[(2 * m) * TT + j]) * 0.03125f;
    float e1 = __expf(trans[(2 * m + 1) * TT + j]) * 0.03125f;
    E2[m] = __builtin_amdgcn_cvt_pkrtz(e0, e1);
  }

  const float* ep = em + (size_t)b * SS * TT + j;
  const int* mp = mask + b * SS;

  // init: alpha0 = start + em[0]; q = exp(alpha0 - alpha0[0]) * 2^-6
  float a0v = startT[j] + ep[0];
  float a00 = rfl_f(a0v);
  float q = __expf(a0v - a00) * 0.015625f;
  float gamma0 = a00 * 1.4426950408889634f + 6.0f;
  int esum = 0, nsteps = 0;

  // steps i = 1..2047 as 256 chunks of 8 (chunk 255 pads step 2048, masked off)
  float bufA[8], bufB[8];
  int mA, mB;
  prefetch8(bufA, mA, 1, ep, mp, j);
  for (int c = 0; c < 256; c += 2) {
    prefetch8(bufB, mB, 1 + 8 * (c + 1), ep, mp, j);
    process8(q, esum, nsteps, bufA, mA, E2);
    prefetch8(bufA, mA, 1 + 8 * (c + 2), ep, mp, j);  // c+2==256: fully masked
    process8(q, esum, nsteps, bufB, mB, E2);
  }

  // denominator = logsumexp_j(alpha_j + end_j)
  float gamma = gamma0 + (float)esum - 116.0f * (float)nsteps;
  float alpha = (__log2f(q) + gamma) * 0.69314718055994531f;
  float tj = alpha + endT[j];
  float mx = tj;
#pragma unroll
  for (int o = 32; o > 0; o >>= 1) mx = fmaxf(mx, __shfl_xor(mx, o, 64));
  float ex = __expf(tj - mx);
#pragma unroll
  for (int o = 32; o > 0; o >>= 1) ex += __shfl_xor(ex, o, 64);
  float den = mx + __logf(ex);

  if (j == 0) {
    int cnt = cntArr[b];
    float nm = numerArr[b] + endT[tags[b * SS + cnt - 1]];
    atomicAdd(out, (den - nm) * (1.0f / BB));
  }
}

// Numerator partials: 2048 blocks (8 per batch) x 256 threads, 1 timestep/thread.
__global__ __launch_bounds__(256) void crf_num_kernel(
    const float* __restrict__ em, const float* __restrict__ startT,
    const float* __restrict__ trans, const int* __restrict__ tags,
    const int* __restrict__ mask, float* __restrict__ numerArr,
    int* __restrict__ cntArr) {
  const int b = blockIdx.x >> 3;
  const int i = ((blockIdx.x & 7) << 8) | threadIdx.x;
  const int* tg = tags + b * SS;
  const float* e = em + (size_t)b * SS * TT;
  int tgi = tg[i];
  int m = mask[b * SS + i];
  int cnt = m;
  float part;
  if (i == 0)
    part = startT[tgi] + e[tgi];
  else if (m)
    part = trans[tg[i - 1] * TT + tgi] + e[(size_t)i * TT + tgi];
  else
    part = 0.f;
#pragma unroll
  for (int o = 32; o > 0; o >>= 1) {
    part += __shfl_down(part, o, 64);
    cnt += __shfl_down(cnt, o, 64);
  }
  __shared__ float sp[4];
  __shared__ int sc[4];
  int wid = threadIdx.x >> 6;
  if ((threadIdx.x & 63) == 0) { sp[wid] = part; sc[wid] = cnt; }
  __syncthreads();
  if (threadIdx.x == 0) {
    atomicAdd(&numerArr[b], sp[0] + sp[1] + sp[2] + sp[3]);
    atomicAdd(&cntArr[b], sc[0] + sc[1] + sc[2] + sc[3]);
  }
}

extern "C" void kernel_launch(void* const* d_in, const int* in_sizes, int n_in,
                              void* d_out, int out_size, void* d_ws, size_t ws_size,
                              hipStream_t stream) {
  const float* em = (const float*)d_in[0];
  const float* startT = (const float*)d_in[1];
  const float* endT = (const float*)d_in[2];
  const float* trans = (const float*)d_in[3];
  const int* tags = (const int*)d_in[4];
  const int* mask = (const int*)d_in[5];
  float* out = (float*)d_out;
  float* numerArr = (float*)d_ws;                  // 256 floats
  int* cntArr = (int*)((char*)d_ws + 1024);        // 256 ints

  (void)hipMemsetAsync(out, 0, sizeof(float), stream);
  (void)hipMemsetAsync(d_ws, 0, 2048, stream);
  crf_num_kernel<<<BB * 8, 256, 0, stream>>>(em, startT, trans, tags, mask,
                                             numerArr, cntArr);
  crf_den_kernel<<<BB, 64, 0, stream>>>(em, startT, endT, trans, mask, tags,
                                        numerArr, cntArr, out);
}